// Round 7
// baseline (74.627 us; speedup 1.0000x reference)
//
#include <hip/hip_runtime.h>
#include <math.h>

// Kuramoto fp8-MFMA, round 7: R6 minus the pack_k dispatch (K converted in-prologue),
// with t-major step body: read all B once -> per-tile {MFMA, update, pack, write
// NEXT step's staging}. Tile-0's staging write overlaps tile-1's MFMAs; single
// barrier/step directly before the reads. 2-buffer scheme race-free:
// writes at step s go to buf[(s+1)&1]; all reads of that buffer happen strictly
// after barrier(s+1), and rewrites of buf[s&1] happen only after barrier(s+1)
// which every wave reaches only after finishing its buf[s&1] reads.
//
// GEMM (transposed): G^T = K . S^T; A = K fp8 (VGPR-resident frags), B = staged
// sin/cos fp8 (16B unit = [S(8 osc)|C(8 osc)], phys = u ^ l15 swizzle).
// Rotation update: (sin,cos) advanced by small-angle poly (|d|<=0.06, err ~6e-9);
// no transcendentals in the loop. Layouts HW-verified by R2-R6 passing.
// absmax floor = 1 bf16 ulp (0.015625) from the harness's bf16 comparison.

typedef __attribute__((ext_vector_type(4))) float f32x4;
typedef __attribute__((ext_vector_type(2))) long long2_t;

constexpr int N       = 256;
constexpr int RB      = 16;     // batch rows per block -> 64 blocks (structural cap)
constexpr int STEPS   = 10;
constexpr int WAVES   = 8;
constexpr int THREADS = WAVES * 64;
constexpr float DT    = 0.1f;
constexpr float TWO_PI     = 6.28318530717958648f;
constexpr float INV_TWO_PI = 0.15915494309189535f;

__global__ __launch_bounds__(THREADS, 2)
void kuramoto_r7(const float* __restrict__ theta0,
                 const float* __restrict__ Kmat,
                 const float* __restrict__ omega,
                 const float* __restrict__ kglob,
                 float* __restrict__ theta_out,
                 float* __restrict__ coh_out)
{
    // [buf][row l15 * 512B]; 32 units/row of 16B = [S(8)|C(8)]; phys = u ^ l15.
    __shared__ __align__(16) unsigned char SC[2][RB * 512];
    __shared__ float redS[RB][WAVES], redC[RB][WAVES];

    const int tid  = threadIdx.x;
    const int wv   = tid >> 6;      // wave -> osc slab [32wv, 32wv+32), tiles 2wv, 2wv+1
    const int lane = tid & 63;
    const int q    = lane >> 4;
    const int l15  = lane & 15;     // batch-in-block (B-frag n / D col)
    const int b0   = blockIdx.x * RB;

    const float kgn = kglob[0] * (1.0f / 256.0f);

    // ---- K -> fp8 A-frags in-prologue: kf[t][c] = A[m=l15][k=32c+8q+jj], tile 2wv+t ----
    long kf[2][8];
#pragma unroll
    for (int t = 0; t < 2; ++t) {
        const float* kr = Kmat + (size_t)(16 * (2 * wv + t) + l15) * N + 8 * q;
#pragma unroll
        for (int c = 0; c < 8; ++c) {
            float4 lo = *(const float4*)(kr + 32 * c);
            float4 hi = *(const float4*)(kr + 32 * c + 4);
            int w0 = __builtin_amdgcn_cvt_pk_fp8_f32(lo.x, lo.y, 0, false);
            w0     = __builtin_amdgcn_cvt_pk_fp8_f32(lo.z, lo.w, w0, true);
            int w1 = __builtin_amdgcn_cvt_pk_fp8_f32(hi.x, hi.y, 0, false);
            w1     = __builtin_amdgcn_cvt_pk_fp8_f32(hi.z, hi.w, w1, true);
            kf[t][c] = (long)(unsigned)w0 | ((long)w1 << 32);
        }
    }

    // ---- rotation state: 8 osc/thread (t=0,1; r=0..3 at osc 32wv+16t+4q+r) ----
    float th[8], om[8], sn[8], cs[8];
#pragma unroll
    for (int t = 0; t < 2; ++t) {
        const int ob = 32 * wv + 16 * t + 4 * q;
        float4 t4 = *(const float4*)(theta0 + (size_t)(b0 + l15) * N + ob);
        float4 o4 = *(const float4*)(omega + ob);
        th[4*t+0] = t4.x; th[4*t+1] = t4.y; th[4*t+2] = t4.z; th[4*t+3] = t4.w;
        om[4*t+0] = o4.x; om[4*t+1] = o4.y; om[4*t+2] = o4.z; om[4*t+3] = o4.w;
    }
#pragma unroll
    for (int k = 0; k < 8; ++k)
        __sincosf(th[k], &sn[k], &cs[k]);

    const int so = 4 * (q & 1);          // dword slot within unit half
    const int g0 = 4 * wv + (q >> 1);    // staging unit of tile t=0 (t adds 2)

    // ---- stage step-0 sin/cos into buf 0 ----
#pragma unroll
    for (int t = 0; t < 2; ++t) {
        int spk = __builtin_amdgcn_cvt_pk_fp8_f32(sn[4*t+0], sn[4*t+1], 0, false);
        spk     = __builtin_amdgcn_cvt_pk_fp8_f32(sn[4*t+2], sn[4*t+3], spk, true);
        int cpk = __builtin_amdgcn_cvt_pk_fp8_f32(cs[4*t+0], cs[4*t+1], 0, false);
        cpk     = __builtin_amdgcn_cvt_pk_fp8_f32(cs[4*t+2], cs[4*t+3], cpk, true);
        const int base = (((g0 + 2 * t) ^ l15) << 4);
        *(int*)(&SC[0][l15 * 512] + base + so)     = spk;
        *(int*)(&SC[0][l15 * 512] + base + 8 + so) = cpk;
    }

    for (int s = 0; s < STEPS; ++s) {
        __syncthreads();   // buf[s&1] fully staged by all waves
        const unsigned char* rdp = &SC[s & 1][l15 * 512];
        unsigned char*       wrp = &SC[(s + 1) & 1][l15 * 512];

        // ---- read all B once (8 x b128 -> {Bs,Bc} pairs) ----
        long2_t v[8];
#pragma unroll
        for (int c = 0; c < 8; ++c)
            v[c] = *(const long2_t*)(rdp + ((((4 * c + q) ^ l15)) << 4));

        // ---- t-major: MFMA -> update -> pack -> write next staging, per tile ----
#pragma unroll
        for (int t = 0; t < 2; ++t) {
            f32x4 aS = (f32x4){0.f, 0.f, 0.f, 0.f};
            f32x4 aC = (f32x4){0.f, 0.f, 0.f, 0.f};
#pragma unroll
            for (int c = 0; c < 8; ++c) {
                aS = __builtin_amdgcn_mfma_f32_16x16x32_fp8_fp8(kf[t][c], v[c].x, aS, 0, 0, 0);
                aC = __builtin_amdgcn_mfma_f32_16x16x32_fp8_fp8(kf[t][c], v[c].y, aC, 0, 0, 0);
            }
#pragma unroll
            for (int r = 0; r < 4; ++r) {
                const int k = 4 * t + r;
                float coup = cs[k] * aS[r] - sn[k] * aC[r];
                float d  = DT * fmaf(kgn, coup, om[k]);
                float d2 = d * d;
                float sd = d * fmaf(d2, -1.0f / 6.0f, 1.0f);              // sin(d)
                float cd = fmaf(d2, fmaf(d2, 1.0f / 24.0f, -0.5f), 1.0f); // cos(d)
                float s2 = fmaf(sn[k], cd,  cs[k] * sd);
                float c2 = fmaf(cs[k], cd, -sn[k] * sd);
                sn[k] = s2; cs[k] = c2; th[k] += d;
            }
            // stage tile t for step s+1 (overlaps the other tile's MFMAs)
            int spk = __builtin_amdgcn_cvt_pk_fp8_f32(sn[4*t+0], sn[4*t+1], 0, false);
            spk     = __builtin_amdgcn_cvt_pk_fp8_f32(sn[4*t+2], sn[4*t+3], spk, true);
            int cpk = __builtin_amdgcn_cvt_pk_fp8_f32(cs[4*t+0], cs[4*t+1], 0, false);
            cpk     = __builtin_amdgcn_cvt_pk_fp8_f32(cs[4*t+2], cs[4*t+3], cpk, true);
            const int base = (((g0 + 2 * t) ^ l15) << 4);
            *(int*)(wrp + base + so)     = spk;
            *(int*)(wrp + base + 8 + so) = cpk;
        }
    }

    // ---- epilogue: wrap, float4 stores, coherence from live (s,c) ----
    float ps = 0.f, pc = 0.f;
#pragma unroll
    for (int t = 0; t < 2; ++t) {
        const int ob = 32 * wv + 16 * t + 4 * q;
        float4 outv;
        outv.x = fmaf(-TWO_PI, rintf(th[4*t+0] * INV_TWO_PI), th[4*t+0]);
        outv.y = fmaf(-TWO_PI, rintf(th[4*t+1] * INV_TWO_PI), th[4*t+1]);
        outv.z = fmaf(-TWO_PI, rintf(th[4*t+2] * INV_TWO_PI), th[4*t+2]);
        outv.w = fmaf(-TWO_PI, rintf(th[4*t+3] * INV_TWO_PI), th[4*t+3]);
        *(float4*)(theta_out + (size_t)(b0 + l15) * N + ob) = outv;
#pragma unroll
        for (int r = 0; r < 4; ++r) { ps += sn[4*t+r]; pc += cs[4*t+r]; }
    }
    ps += __shfl_xor(ps, 16, 64);  pc += __shfl_xor(pc, 16, 64);
    ps += __shfl_xor(ps, 32, 64);  pc += __shfl_xor(pc, 32, 64);
    if (q == 0) { redS[l15][wv] = ps; redC[l15][wv] = pc; }
    __syncthreads();
    if (tid < RB) {
        float S = 0.f, C = 0.f;
#pragma unroll
        for (int k = 0; k < WAVES; ++k) { S += redS[tid][k]; C += redC[tid][k]; }
        float sm = S * (1.0f / 256.0f);
        float cm = C * (1.0f / 256.0f);
        coh_out[b0 + tid] = sqrtf(sm * sm + cm * cm);
    }
}

extern "C" void kernel_launch(void* const* d_in, const int* in_sizes, int n_in,
                              void* d_out, int out_size, void* d_ws, size_t ws_size,
                              hipStream_t stream) {
    const float* theta0 = (const float*)d_in[0];
    const float* Kmat   = (const float*)d_in[1];
    const float* omega  = (const float*)d_in[2];
    const float* kglob  = (const float*)d_in[3];

    float* theta_out = (float*)d_out;            // 1024*256
    float* coh_out   = theta_out + 1024 * N;     // then 1024

    kuramoto_r7<<<dim3(1024 / RB), dim3(THREADS), 0, stream>>>(
        theta0, Kmat, omega, kglob, theta_out, coh_out);
}